// Round 10
// baseline (184.162 us; speedup 1.0000x reference)
//
#include <hip/hip_runtime.h>
#include <hip/hip_bf16.h>
#include <math.h>

#define B   8
#define S   64
#define NL  128
#define NPRO 256
#define NN  384   // NL + NPRO
#define P   64
#define NGRP 8
#define EPSF 1e-6f

// ---------------------------------------------------------------------------
// Kernel 1: mean_len[b,s]
// ---------------------------------------------------------------------------
__global__ __launch_bounds__(64) void meanlen_kernel(
    const float* __restrict__ lig, const float* __restrict__ ligmask,
    const float* __restrict__ pro, const float* __restrict__ promask,
    float* __restrict__ meanlen)
{
    int blk = blockIdx.x;              // b*S + s
    int t = threadIdx.x;
    float suml = 0.f, cnt = 0.f;

    const float* lbase = lig + (size_t)blk * NL * 3;
    const float* lm    = ligmask + (size_t)blk * NL;
    for (int n = t; n < NL; n += 64) {
        float x = lbase[n*3+0], y = lbase[n*3+1], z = lbase[n*3+2];
        float mk = lm[n];
        suml += sqrtf(x*x + y*y + z*z) * mk;
        cnt  += mk;
    }
    const float* pbase = pro + (size_t)blk * NPRO * 3;
    const float* pm    = promask + (size_t)blk * NPRO;
    for (int n = t; n < NPRO; n += 64) {
        float x = pbase[n*3+0], y = pbase[n*3+1], z = pbase[n*3+2];
        float mk = pm[n];
        suml += sqrtf(x*x + y*y + z*z) * mk;
        cnt  += mk;
    }
    for (int off = 32; off > 0; off >>= 1) {
        suml += __shfl_down(suml, off);
        cnt  += __shfl_down(cnt,  off);
    }
    if (t == 0) meanlen[blk] = suml / cnt;
}

// ---------------------------------------------------------------------------
// Kernel 2: SoA projection planes
// ---------------------------------------------------------------------------
__global__ __launch_bounds__(64) void proj_kernel(
    const float* __restrict__ lig, const float* __restrict__ pro,
    const float* __restrict__ ligmask, const float* __restrict__ promask,
    const float* __restrict__ ligw, const float* __restrict__ prow,
    const float* __restrict__ sw, const float* __restrict__ meanlen,
    float* __restrict__ projx, float* __restrict__ projy, float* __restrict__ projz)
{
    int blk = blockIdx.x;
    int b = blk / (NN / NGRP);
    int g = blk - b * (NN / NGRP);
    int nbase = g * NGRP;
    int t = threadIdx.x;
    bool isl = (nbase < NL);

    __shared__ float wl[64][65];           // wl[p][s], padded
    const float* w = isl ? ligw : prow;    // (P,S)
    for (int row = 0; row < 64; ++row) wl[row][t] = w[row * 64 + t];

    __shared__ float cs[NGRP][3][64];      // coords premultiplied by g-factor
    {
        int s = t;
        float gfac = sw[s] / (meanlen[b * S + s] + EPSF);
        for (int nn = 0; nn < NGRP; ++nn) {
            int n = nbase + nn;
            float mk, X, Y, Z;
            if (isl) {
                size_t base = ((size_t)b * S + s) * NL + n;
                mk = ligmask[base];
                X = lig[base*3+0]; Y = lig[base*3+1]; Z = lig[base*3+2];
            } else {
                size_t base = ((size_t)b * S + s) * NPRO + (n - NL);
                mk = promask[base];
                X = pro[base*3+0]; Y = pro[base*3+1]; Z = pro[base*3+2];
            }
            float gg = gfac * mk;
            cs[nn][0][s] = X * gg;
            cs[nn][1][s] = Y * gg;
            cs[nn][2][s] = Z * gg;
        }
    }
    __syncthreads();

    for (int nn = 0; nn < NGRP; ++nn) {
        float a0 = 0.f, a1 = 0.f, a2 = 0.f;
        #pragma unroll 8
        for (int s = 0; s < 64; ++s) {
            float wv = wl[t][s];
            a0 += cs[nn][0][s] * wv;
            a1 += cs[nn][1][s] * wv;
            a2 += cs[nn][2][s] * wv;
        }
        size_t base = ((size_t)b * NN + nbase + nn) * P;
        projx[base + t] = a0;
        projy[base + t] = a1;
        projz[base + t] = a2;
    }
}

// ---------------------------------------------------------------------------
// Kernel 3 (dominant, pass 1): block = (b, n-slice of 24, i-chunk of 8).
// k-outer / i-pair-inner: ONE pl[k][p] ds_read_b128 feeds BOTH i of the
// wave's pair (halves b128 issue); adj mask via wave-uniform SCALAR loads
// (s_load + SALU select, zero LDS / zero VALU). After the single staging
// barrier waves are independent. grid = 8 x 16 x 16 = 2048 blocks x 256 thr.
// ---------------------------------------------------------------------------
#define BODY(XX,YY,ZZ, MV, AM, S1,S2,A0,A1,A2) { \
    float d0 = XX - xn.x, d1 = YY - xn.y, d2 = ZZ - xn.z; \
    float sq = fmaf(d0, d0, fmaf(d1, d1, d2 * d2)); \
    float inv; asm("v_rsq_f32 %0, %1" : "=v"(inv) : "v"(sq)); \
    inv = fminf(inv, 1e30f); \
    float xe = fmaf(MV, 1.44269504f, AM); \
    float e; asm("v_exp_f32 %0, %1" : "=v"(e) : "v"(xe)); \
    float ei = e * inv; \
    S1 += e; S2 = fmaf(e, e, S2); \
    A0 = fmaf(ei, d0, A0); A1 = fmaf(ei, d1, A1); A2 = fmaf(ei, d2, A2); }

__global__ __launch_bounds__(256, 4) void partial_kernel(
    const float* __restrict__ messages,   // (B, NL, NN, P)
    const int*   __restrict__ adj,        // (B, NL, NN)
    const float* __restrict__ projx,      // (B, NN, P)
    const float* __restrict__ projy,
    const float* __restrict__ projz,
    float* __restrict__ partial,          // (B*NL, 16, 5, 64)
    int passes)
{
    int blk = blockIdx.x;          // b*256 + nsl*16 + ic
    int b   = blk >> 8;
    int nsl = (blk >> 4) & 15;
    int ic  = blk & 15;
    int t = threadIdx.x;
    int wave = t >> 6;             // 0..3
    int p = t & 63;
    int n0 = nsl * 24;

    __shared__ __align__(16) float4 pl[24][64];   // proj (x,y,z,-) : 24.6 KB

    for (int idx = t; idx < 24 * 64; idx += 256) {
        int k = idx >> 6, pp = idx & 63;
        size_t g = ((size_t)b * NN + n0 + k) * 64 + pp;
        pl[k][pp] = make_float4(projx[g], projy[g], projz[g], 0.f);
    }
    __syncthreads();   // only barrier; waves independent afterwards

    int ia = ic * 8 + wave * 2;    // this wave's i-pair
    size_t rowa = (size_t)b * NL + ia;
    size_t rowb = rowa + 1;
    const int* adja = adj + rowa * NN + n0;   // wave-uniform -> scalar loads
    const int* adjb = adj + rowb * NN + n0;

    #pragma unroll 1
    for (int pass = 0; pass < passes; ++pass) {
        asm volatile("" ::: "memory");   // keep diag passes live

        size_t xaidx = ((size_t)b * NN + ia) * 64 + p;
        float xax = projx[xaidx], xay = projy[xaidx], xaz = projz[xaidx];
        float xbx = projx[xaidx + 64], xby = projy[xaidx + 64], xbz = projz[xaidx + 64];

        float s1a=0.f,s2a=0.f,a0a=0.f,a1a=0.f,a2a=0.f;
        float s1b=0.f,s2b=0.f,a0b=0.f,a1b=0.f,a2b=0.f;

        const float* ma = messages + (rowa * NN + n0) * 64 + p;
        const float* mb = messages + (rowb * NN + n0) * 64 + p;

        #pragma unroll
        for (int h = 0; h < 2; ++h) {
            float m0[12], m1[12];
            #pragma unroll
            for (int k = 0; k < 12; ++k) {
                m0[k] = ma[(size_t)(h * 12 + k) * 64];
                m1[k] = mb[(size_t)(h * 12 + k) * 64];
            }
            #pragma unroll
            for (int k = 0; k < 12; ++k) {
                int kk = h * 12 + k;
                float4 xn = pl[kk][p];                       // 1 b128 for both i
                float am0 = adja[kk] > 0 ? 0.f : -INFINITY;  // scalar path
                float am1 = adjb[kk] > 0 ? 0.f : -INFINITY;
                BODY(xax,xay,xaz, m0[k], am0, s1a,s2a,a0a,a1a,a2a)
                BODY(xbx,xby,xbz, m1[k], am1, s1b,s2b,a0b,a1b,a2b)
            }
        }

        float* da = partial + ((rowa * 16 + nsl) * 5) * 64 + p;
        da[0]=s1a; da[64]=s2a; da[128]=a0a; da[192]=a1a; da[256]=a2a;
        float* db = partial + ((rowb * 16 + nsl) * 5) * 64 + p;
        db[0]=s1b; db[64]=s2b; db[128]=a0b; db[192]=a1b; db[256]=a2b;
    }
}

// ---------------------------------------------------------------------------
// Kernel 4 (pass 2): combine 16 n-partials (4 groups x 4 nh in parallel),
// apply sqrt(S2)/S1^2, project to s. grid = B*NL blocks x 256 threads.
// ---------------------------------------------------------------------------
__global__ __launch_bounds__(256) void combine_kernel(
    const float* __restrict__ partial,    // (B*NL, 16, 5, 64)
    const float* __restrict__ attn_w,     // (S, P)
    float* __restrict__ out,              // (B, S, NL, 3)
    int passes)
{
    int blk = blockIdx.x;        // b*NL + i
    int b = blk >> 7;
    int i = blk & (NL - 1);
    int t = threadIdx.x;
    int g = t >> 6;              // 0..3 (nh group)
    int p = t & 63;

    __shared__ float red[4][5][64];
    __shared__ float upd[3][64];

    #pragma unroll 1
    for (int pass = 0; pass < passes; ++pass) {
        asm volatile("" ::: "memory");

        float s1 = 0.f, s2 = 0.f, a0 = 0.f, a1 = 0.f, a2 = 0.f;
        #pragma unroll
        for (int j = 0; j < 4; ++j) {
            int nh = g + j * 4;
            size_t base = (((size_t)blk * 16 + nh) * 5) * 64 + p;
            s1 += partial[base];
            s2 += partial[base + 64];
            a0 += partial[base + 128];
            a1 += partial[base + 192];
            a2 += partial[base + 256];
        }
        red[g][0][p] = s1; red[g][1][p] = s2;
        red[g][2][p] = a0; red[g][3][p] = a1; red[g][4][p] = a2;
        __syncthreads();

        if (t < 64) {
            float S1 = red[0][0][t] + red[1][0][t] + red[2][0][t] + red[3][0][t];
            float S2 = red[0][1][t] + red[1][1][t] + red[2][1][t] + red[3][1][t];
            float A0 = red[0][2][t] + red[1][2][t] + red[2][2][t] + red[3][2][t];
            float A1 = red[0][3][t] + red[1][3][t] + red[2][3][t] + red[3][3][t];
            float A2 = red[0][4][t] + red[1][4][t] + red[2][4][t] + red[3][4][t];
            float wgt = sqrtf(S2) / (S1 * S1);   // (A/S1)*sqrt(S2)/S1
            upd[0][t] = A0 * wgt;
            upd[1][t] = A1 * wgt;
            upd[2][t] = A2 * wgt;
        }
        __syncthreads();

        if (t < 192) {
            int s = t & 63, c = t >> 6;
            const float4* aw4 = (const float4*)attn_w + (size_t)s * 16;
            float o = 0.f;
            #pragma unroll
            for (int q = 0; q < 16; ++q) {
                float4 w4 = aw4[q];
                o = fmaf(upd[c][q*4+0], w4.x, o);
                o = fmaf(upd[c][q*4+1], w4.y, o);
                o = fmaf(upd[c][q*4+2], w4.z, o);
                o = fmaf(upd[c][q*4+3], w4.w, o);
            }
            out[(((size_t)b * S + s) * NL + i) * 3 + c] = o;
        }
        __syncthreads();
    }
}

extern "C" void kernel_launch(void* const* d_in, const int* in_sizes, int n_in,
                              void* d_out, int out_size, void* d_ws, size_t ws_size,
                              hipStream_t stream)
{
    const float* lig      = (const float*)d_in[0];   // (B,S,NL,3)
    const float* messages = (const float*)d_in[1];   // (B,NL,NN,P)
    const int*   adj      = (const int*)  d_in[2];   // (B,NL,NN)
    const float* ligmask  = (const float*)d_in[3];   // (B,S,NL)
    const float* pro      = (const float*)d_in[4];   // (B,S,NPRO,3)
    const float* promask  = (const float*)d_in[5];   // (B,S,NPRO)
    const float* ligw     = (const float*)d_in[6];   // (P,S)
    const float* prow     = (const float*)d_in[7];   // (P,S)
    const float* attnw    = (const float*)d_in[8];   // (S,P)
    const float* sw       = (const float*)d_in[9];   // (S,)
    float* out = (float*)d_out;

    const size_t plane = (size_t)B * NN * P;         // 196608 floats
    float* meanlen = (float*)d_ws;                               // 2 KB
    float* projx   = (float*)((char*)d_ws + 2048);
    float* projy   = projx + plane;
    float* projz   = projy + plane;
    float* partial = (float*)((char*)d_ws + (4u << 20));         // 21 MB @ 4MB

    meanlen_kernel<<<B * S, 64, 0, stream>>>(lig, ligmask, pro, promask, meanlen);
    proj_kernel<<<B * (NN / NGRP), 64, 0, stream>>>(lig, pro, ligmask, promask,
                                                    ligw, prow, sw, meanlen,
                                                    projx, projy, projz);
    partial_kernel<<<B * 16 * 16, 256, 0, stream>>>(messages, adj,
                                                    projx, projy, projz,
                                                    partial, 1);
    combine_kernel<<<B * NL, 256, 0, stream>>>(partial, attnw, out, 1);

    // --- diagnostics (write to high scratch; multi-pass to rank above fills) ---
    if (ws_size >= (96u << 20)) {
        float* diagp = (float*)((char*)d_ws + (32u << 20));   // 21 MB
        float* diagc = (float*)((char*)d_ws + (64u << 20));   // 768 KB
        partial_kernel<<<B * 16 * 16, 256, 0, stream>>>(messages, adj,
                                                        projx, projy, projz,
                                                        diagp, 4);
        combine_kernel<<<B * NL, 256, 0, stream>>>(partial, attnw, diagc, 8);
    }
}